// Round 9
// baseline (666.659 us; speedup 1.0000x reference)
//
#include <hip/hip_runtime.h>

// Batched Kalman step: G groups, S=16, M=8, fp32.
// R9 = R8 (one group per 4-lane quad, zero LDS/DS, DPP quad-broadcast GEMMs)
// with the register peak cut 192 -> ~150:
//  - W = F@NC and pred_cov = W@F^T + Q fused per output row (W never
//    materialized; removes the 64-reg double buffer)
//  - __launch_bounds__(256, 3): cap VGPR at 170 -> 3 waves/SIMD guaranteed
//    (R4 spill tripwire: WRITE_SIZE must stay ~139-144 MB)

__device__ __forceinline__ float bq(float x, int t) {
    // broadcast lane t of each quad (DPP quad_perm, ctrl = t*0x55)
    switch (t & 3) {
    case 0:  return __int_as_float(__builtin_amdgcn_mov_dpp(__float_as_int(x), 0x00, 0xF, 0xF, true));
    case 1:  return __int_as_float(__builtin_amdgcn_mov_dpp(__float_as_int(x), 0x55, 0xF, 0xF, true));
    case 2:  return __int_as_float(__builtin_amdgcn_mov_dpp(__float_as_int(x), 0xAA, 0xF, 0xF, true));
    default: return __int_as_float(__builtin_amdgcn_mov_dpp(__float_as_int(x), 0xFF, 0xF, 0xF, true));
    }
}

__global__ __launch_bounds__(256, 3) void kalman_kernel(
    const float* __restrict__ g_in,
    const float* __restrict__ g_mean,
    const float* __restrict__ g_cov,
    const float* __restrict__ g_H,
    const float* __restrict__ g_R,
    const float* __restrict__ g_F,
    const float* __restrict__ g_Q,
    float* __restrict__ g_out,
    int G)
{
    const int l = threadIdx.x & 3;                         // lane in quad
    const int g = (blockIdx.x << 6) | (threadIdx.x >> 2);  // group id

    const float* const Pp = g_cov + (size_t)g * 256;
    const float* const Hp = g_H   + (size_t)g * 128;
    const float* const Rp = g_R   + (size_t)g * 64;
    const float* const Fp = g_F   + (size_t)g * 256;
    const float* const Qp = g_Q   + (size_t)g * 256;

    // ---- batch loads (coalesced float4 / float2) ----
    float P[16][4];                       // P[k][u] = cov[k][4l+u]
    #pragma unroll
    for (int k = 0; k < 16; ++k) {
        const float4 t = *reinterpret_cast<const float4*>(Pp + k*16 + 4*l);
        P[k][0]=t.x; P[k][1]=t.y; P[k][2]=t.z; P[k][3]=t.w;
    }
    float HT[16][2];                      // HT[k][v] = H[2l+v][k]
    #pragma unroll
    for (int v = 0; v < 2; ++v)
    #pragma unroll
    for (int p = 0; p < 4; ++p) {
        const float4 t = *reinterpret_cast<const float4*>(Hp + (2*l+v)*16 + 4*p);
        HT[4*p+0][v]=t.x; HT[4*p+1][v]=t.y; HT[4*p+2][v]=t.z; HT[4*p+3][v]=t.w;
    }
    float S[8][2];                        // S[i][v] init R[i][2l+v]
    #pragma unroll
    for (int i = 0; i < 8; ++i) {
        const float2 t = *reinterpret_cast<const float2*>(Rp + i*8 + 2*l);
        S[i][0]=t.x; S[i][1]=t.y;
    }
    float mn[4];
    { const float4 t = *reinterpret_cast<const float4*>(g_mean + (size_t)g*16 + 4*l);
      mn[0]=t.x; mn[1]=t.y; mn[2]=t.z; mn[3]=t.w; }
    float ip[2];
    { const float2 t = *reinterpret_cast<const float2*>(g_in + (size_t)g*8 + 2*l);
      ip[0]=t.x; ip[1]=t.y; }

    // ---- CT = H @ P  (8x16 col-slab; H[i][k] = bq(HT[k][i&1], i>>1)) ----
    float CT[8][4];
    #pragma unroll
    for (int i = 0; i < 8; ++i) {
        float a0=0.f, a1=0.f, a2=0.f, a3=0.f;
        #pragma unroll
        for (int k = 0; k < 16; ++k) {
            const float h = bq(HT[k][i&1], i>>1);
            a0 += h*P[k][0]; a1 += h*P[k][1]; a2 += h*P[k][2]; a3 += h*P[k][3];
        }
        CT[i][0]=a0; CT[i][1]=a1; CT[i][2]=a2; CT[i][3]=a3;
    }

    // ---- S = CT @ H^T + R  (CT[i][k] = bq(CT[i][k&3], k>>2)) ----
    #pragma unroll
    for (int i = 0; i < 8; ++i) {
        float a0=S[i][0], a1=S[i][1];
        #pragma unroll
        for (int k = 0; k < 16; ++k) {
            const float c = bq(CT[i][k&3], k>>2);
            a0 += c*HT[k][0]; a1 += c*HT[k][1];
        }
        S[i][0]=a0; S[i][1]=a1;
    }

    // ---- res = inp - H @ mean  (rows 2l,2l+1 per lane) ----
    float resd[2];
    {
        float a0 = ip[0], a1 = ip[1];
        #pragma unroll
        for (int k = 0; k < 16; ++k) {
            const float m = bq(mn[k&3], k>>2);
            a0 -= HT[k][0]*m; a1 -= HT[k][1]*m;
        }
        resd[0]=a0; resd[1]=a1;
    }

    // ---- Gauss-Jordan [S | I] -> Sinv (SPD, no pivoting, divergence-free) ----
    float Ii[8][2];
    #pragma unroll
    for (int i = 0; i < 8; ++i) {
        Ii[i][0] = (2*l   == i) ? 1.f : 0.f;
        Ii[i][1] = (2*l+1 == i) ? 1.f : 0.f;
    }
    float pinvD[8];
    #pragma unroll
    for (int k = 0; k < 8; ++k) {
        const float pv   = bq(S[k][k&1], k>>1);
        const float pinv = __builtin_amdgcn_rcpf(pv);
        pinvD[k] = pinv;
        #pragma unroll
        for (int i = 0; i < 8; ++i) {
            if (i == k) continue;            // compile-time skip
            const float fi = bq(S[i][k&1], k>>1) * pinv;
            S[i][0]  -= fi * S[k][0];   S[i][1]  -= fi * S[k][1];
            Ii[i][0] -= fi * Ii[k][0];  Ii[i][1] -= fi * Ii[k][1];
        }
    }
    #pragma unroll
    for (int i = 0; i < 8; ++i) { Ii[i][0] *= pinvD[i]; Ii[i][1] *= pinvD[i]; }

    // ---- X = Sinv @ CT  (Sinv[m][j] = bq(Ii[m][j&1], j>>1)) ----
    float X[8][4];
    #pragma unroll
    for (int m = 0; m < 8; ++m) {
        float a0=0.f, a1=0.f, a2=0.f, a3=0.f;
        #pragma unroll
        for (int j = 0; j < 8; ++j) {
            const float s = bq(Ii[m][j&1], j>>1);
            a0 += s*CT[j][0]; a1 += s*CT[j][1]; a2 += s*CT[j][2]; a3 += s*CT[j][3];
        }
        X[m][0]=a0; X[m][1]=a1; X[m][2]=a2; X[m][3]=a3;
    }

    // ---- nm = mean + X^T res  (res[m] = bq(resd[m&1], m>>1)) ----
    float nmv[4] = {mn[0], mn[1], mn[2], mn[3]};
    #pragma unroll
    for (int m = 0; m < 8; ++m) {
        const float r = bq(resd[m&1], m>>1);
        nmv[0] += X[m][0]*r; nmv[1] += X[m][1]*r; nmv[2] += X[m][2]*r; nmv[3] += X[m][3]*r;
    }

    // ---- NC = P - CT^T @ X  (in place; CT[m][s] = bq(CT[m][s&3], s>>2)) ----
    #pragma unroll
    for (int s = 0; s < 16; ++s) {
        float a0=P[s][0], a1=P[s][1], a2=P[s][2], a3=P[s][3];
        #pragma unroll
        for (int m = 0; m < 8; ++m) {
            const float c = bq(CT[m][s&3], s>>2);
            a0 -= c*X[m][0]; a1 -= c*X[m][1]; a2 -= c*X[m][2]; a3 -= c*X[m][3];
        }
        P[s][0]=a0; P[s][1]=a1; P[s][2]=a2; P[s][3]=a3;
    }
    // CT, X, S, Ii, HT all dead here.

    // ---- FT loads: FT[t][u] = F[4l+u][t] (per-lane contiguous) ----
    float FT[16][4];
    #pragma unroll
    for (int u = 0; u < 4; ++u)
    #pragma unroll
    for (int p = 0; p < 4; ++p) {
        const float4 t = *reinterpret_cast<const float4*>(Fp + (4*l+u)*16 + 4*p);
        FT[4*p+0][u]=t.x; FT[4*p+1][u]=t.y; FT[4*p+2][u]=t.z; FT[4*p+3][u]=t.w;
    }

    // ---- pred_mean = F @ nm -> coalesced float4 store ----
    {
        float a0=0.f, a1=0.f, a2=0.f, a3=0.f;
        #pragma unroll
        for (int k = 0; k < 16; ++k) {
            const float m = bq(nmv[k&3], k>>2);
            a0 += FT[k][0]*m; a1 += FT[k][1]*m; a2 += FT[k][2]*m; a3 += FT[k][3]*m;
        }
        *reinterpret_cast<float4*>(g_out + (size_t)g*16 + 4*l) = make_float4(a0,a1,a2,a3);
    }

    // ---- pred_cov row-fused: for each row i,
    //      w[u] = W[i][4l+u] = sum_k F[i][k]*NC[k][4l+u]   (F[i][k] via DPP)
    //      out[i][4l+u] = Q[i][4l+u] + sum_t bq(w[t])*FT[t][u]
    //      W never materialized; 2-row Q prefetch; coalesced stores ----
    float* const out_pc = g_out + (size_t)G*16 + (size_t)g*256;
    float4 qa = *reinterpret_cast<const float4*>(Qp + 0*16 + 4*l);
    float4 qb = *reinterpret_cast<const float4*>(Qp + 1*16 + 4*l);
    #pragma unroll
    for (int i = 0; i < 16; ++i) {
        float4 qn = qb;
        if (i < 14) qn = *reinterpret_cast<const float4*>(Qp + (i+2)*16 + 4*l);
        // w = F_i @ NC (col-slab)
        float w0=0.f, w1=0.f, w2=0.f, w3=0.f;
        #pragma unroll
        for (int k = 0; k < 16; ++k) {
            const float f = bq(FT[k][i&3], i>>2);      // F[i][k]
            w0 += f*P[k][0]; w1 += f*P[k][1]; w2 += f*P[k][2]; w3 += f*P[k][3];
        }
        // out_i = w @ F^T + Q_i
        float o0=qa.x, o1=qa.y, o2=qa.z, o3=qa.w;
        #pragma unroll
        for (int t = 0; t < 16; ++t) {
            float wt;
            switch (t & 3) { case 0: wt=w0; break; case 1: wt=w1; break;
                             case 2: wt=w2; break; default: wt=w3; }
            const float wb = bq(wt, t>>2);             // W[i][t]
            o0 += wb*FT[t][0]; o1 += wb*FT[t][1]; o2 += wb*FT[t][2]; o3 += wb*FT[t][3];
        }
        *reinterpret_cast<float4*>(out_pc + i*16 + 4*l) = make_float4(o0,o1,o2,o3);
        qa = qb; qb = qn;
    }
}

extern "C" void kernel_launch(void* const* d_in, const int* in_sizes, int n_in,
                              void* d_out, int out_size, void* d_ws, size_t ws_size,
                              hipStream_t stream) {
    const float* g_in   = (const float*)d_in[0];
    const float* g_mean = (const float*)d_in[1];
    const float* g_cov  = (const float*)d_in[2];
    const float* g_H    = (const float*)d_in[3];
    const float* g_R    = (const float*)d_in[4];
    const float* g_F    = (const float*)d_in[5];
    const float* g_Q    = (const float*)d_in[6];
    float* out = (float*)d_out;
    const int G = in_sizes[2] / 256;     // cov is [G,16,16]
    kalman_kernel<<<G/64, 256, 0, stream>>>(g_in, g_mean, g_cov, g_H, g_R, g_F, g_Q, out, G);
}

// Round 10
// 184.859 us; speedup vs baseline: 3.6063x; 3.6063x over previous
//
#include <hip/hip_runtime.h>

// Batched Kalman step: G groups, S=16, M=8, fp32.
// R10 = R8 structure (one group per 4-lane quad, zero LDS/DS, DPP
// quad-broadcast GEMMs) + R9's W/pred_cov row fusion (removes the 64-reg
// W double buffer), WITHOUT any min-waves launch bound:
//   R4 and R9 both proved __launch_bounds__(256, N) makes the compiler
//   clamp VGPR far below the request (R9: 84 VGPR -> 1 GB spill traffic).
//   Register pressure is controlled by code structure instead; expected
//   natural allocation ~150-170 VGPR -> 3 waves/SIMD (vs R8's 192 -> 2).

__device__ __forceinline__ float bq(float x, int t) {
    // broadcast lane t of each quad (DPP quad_perm, ctrl = t*0x55)
    switch (t & 3) {
    case 0:  return __int_as_float(__builtin_amdgcn_mov_dpp(__float_as_int(x), 0x00, 0xF, 0xF, true));
    case 1:  return __int_as_float(__builtin_amdgcn_mov_dpp(__float_as_int(x), 0x55, 0xF, 0xF, true));
    case 2:  return __int_as_float(__builtin_amdgcn_mov_dpp(__float_as_int(x), 0xAA, 0xF, 0xF, true));
    default: return __int_as_float(__builtin_amdgcn_mov_dpp(__float_as_int(x), 0xFF, 0xF, 0xF, true));
    }
}

__global__ __launch_bounds__(256) void kalman_kernel(
    const float* __restrict__ g_in,
    const float* __restrict__ g_mean,
    const float* __restrict__ g_cov,
    const float* __restrict__ g_H,
    const float* __restrict__ g_R,
    const float* __restrict__ g_F,
    const float* __restrict__ g_Q,
    float* __restrict__ g_out,
    int G)
{
    const int l = threadIdx.x & 3;                         // lane in quad
    const int g = (blockIdx.x << 6) | (threadIdx.x >> 2);  // group id

    const float* const Pp = g_cov + (size_t)g * 256;
    const float* const Hp = g_H   + (size_t)g * 128;
    const float* const Rp = g_R   + (size_t)g * 64;
    const float* const Fp = g_F   + (size_t)g * 256;
    const float* const Qp = g_Q   + (size_t)g * 256;

    // ---- batch loads (coalesced float4 / float2) ----
    float P[16][4];                       // P[k][u] = cov[k][4l+u]
    #pragma unroll
    for (int k = 0; k < 16; ++k) {
        const float4 t = *reinterpret_cast<const float4*>(Pp + k*16 + 4*l);
        P[k][0]=t.x; P[k][1]=t.y; P[k][2]=t.z; P[k][3]=t.w;
    }
    float HT[16][2];                      // HT[k][v] = H[2l+v][k]
    #pragma unroll
    for (int v = 0; v < 2; ++v)
    #pragma unroll
    for (int p = 0; p < 4; ++p) {
        const float4 t = *reinterpret_cast<const float4*>(Hp + (2*l+v)*16 + 4*p);
        HT[4*p+0][v]=t.x; HT[4*p+1][v]=t.y; HT[4*p+2][v]=t.z; HT[4*p+3][v]=t.w;
    }
    float S[8][2];                        // S[i][v] init R[i][2l+v]
    #pragma unroll
    for (int i = 0; i < 8; ++i) {
        const float2 t = *reinterpret_cast<const float2*>(Rp + i*8 + 2*l);
        S[i][0]=t.x; S[i][1]=t.y;
    }
    float mn[4];
    { const float4 t = *reinterpret_cast<const float4*>(g_mean + (size_t)g*16 + 4*l);
      mn[0]=t.x; mn[1]=t.y; mn[2]=t.z; mn[3]=t.w; }
    float ip[2];
    { const float2 t = *reinterpret_cast<const float2*>(g_in + (size_t)g*8 + 2*l);
      ip[0]=t.x; ip[1]=t.y; }

    // ---- CT = H @ P  (8x16 col-slab; H[i][k] = bq(HT[k][i&1], i>>1)) ----
    float CT[8][4];
    #pragma unroll
    for (int i = 0; i < 8; ++i) {
        float a0=0.f, a1=0.f, a2=0.f, a3=0.f;
        #pragma unroll
        for (int k = 0; k < 16; ++k) {
            const float h = bq(HT[k][i&1], i>>1);
            a0 += h*P[k][0]; a1 += h*P[k][1]; a2 += h*P[k][2]; a3 += h*P[k][3];
        }
        CT[i][0]=a0; CT[i][1]=a1; CT[i][2]=a2; CT[i][3]=a3;
    }

    // ---- S = CT @ H^T + R  (CT[i][k] = bq(CT[i][k&3], k>>2)) ----
    #pragma unroll
    for (int i = 0; i < 8; ++i) {
        float a0=S[i][0], a1=S[i][1];
        #pragma unroll
        for (int k = 0; k < 16; ++k) {
            const float c = bq(CT[i][k&3], k>>2);
            a0 += c*HT[k][0]; a1 += c*HT[k][1];
        }
        S[i][0]=a0; S[i][1]=a1;
    }

    // ---- res = inp - H @ mean  (rows 2l,2l+1 per lane) ----
    float resd[2];
    {
        float a0 = ip[0], a1 = ip[1];
        #pragma unroll
        for (int k = 0; k < 16; ++k) {
            const float m = bq(mn[k&3], k>>2);
            a0 -= HT[k][0]*m; a1 -= HT[k][1]*m;
        }
        resd[0]=a0; resd[1]=a1;
    }

    // ---- Gauss-Jordan [S | I] -> Sinv (SPD, no pivoting, divergence-free) ----
    float Ii[8][2];
    #pragma unroll
    for (int i = 0; i < 8; ++i) {
        Ii[i][0] = (2*l   == i) ? 1.f : 0.f;
        Ii[i][1] = (2*l+1 == i) ? 1.f : 0.f;
    }
    float pinvD[8];
    #pragma unroll
    for (int k = 0; k < 8; ++k) {
        const float pv   = bq(S[k][k&1], k>>1);
        const float pinv = __builtin_amdgcn_rcpf(pv);
        pinvD[k] = pinv;
        #pragma unroll
        for (int i = 0; i < 8; ++i) {
            if (i == k) continue;            // compile-time skip
            const float fi = bq(S[i][k&1], k>>1) * pinv;
            S[i][0]  -= fi * S[k][0];   S[i][1]  -= fi * S[k][1];
            Ii[i][0] -= fi * Ii[k][0];  Ii[i][1] -= fi * Ii[k][1];
        }
    }
    #pragma unroll
    for (int i = 0; i < 8; ++i) { Ii[i][0] *= pinvD[i]; Ii[i][1] *= pinvD[i]; }

    // ---- X = Sinv @ CT  (Sinv[m][j] = bq(Ii[m][j&1], j>>1)) ----
    float X[8][4];
    #pragma unroll
    for (int m = 0; m < 8; ++m) {
        float a0=0.f, a1=0.f, a2=0.f, a3=0.f;
        #pragma unroll
        for (int j = 0; j < 8; ++j) {
            const float s = bq(Ii[m][j&1], j>>1);
            a0 += s*CT[j][0]; a1 += s*CT[j][1]; a2 += s*CT[j][2]; a3 += s*CT[j][3];
        }
        X[m][0]=a0; X[m][1]=a1; X[m][2]=a2; X[m][3]=a3;
    }

    // ---- nm = mean + X^T res  (res[m] = bq(resd[m&1], m>>1)) ----
    float nmv[4] = {mn[0], mn[1], mn[2], mn[3]};
    #pragma unroll
    for (int m = 0; m < 8; ++m) {
        const float r = bq(resd[m&1], m>>1);
        nmv[0] += X[m][0]*r; nmv[1] += X[m][1]*r; nmv[2] += X[m][2]*r; nmv[3] += X[m][3]*r;
    }

    // ---- NC = P - CT^T @ X  (in place; CT[m][s] = bq(CT[m][s&3], s>>2)) ----
    #pragma unroll
    for (int s = 0; s < 16; ++s) {
        float a0=P[s][0], a1=P[s][1], a2=P[s][2], a3=P[s][3];
        #pragma unroll
        for (int m = 0; m < 8; ++m) {
            const float c = bq(CT[m][s&3], s>>2);
            a0 -= c*X[m][0]; a1 -= c*X[m][1]; a2 -= c*X[m][2]; a3 -= c*X[m][3];
        }
        P[s][0]=a0; P[s][1]=a1; P[s][2]=a2; P[s][3]=a3;
    }
    // CT, X, S, Ii, HT all dead here.

    // ---- FT loads: FT[t][u] = F[4l+u][t] (per-lane contiguous) ----
    float FT[16][4];
    #pragma unroll
    for (int u = 0; u < 4; ++u)
    #pragma unroll
    for (int p = 0; p < 4; ++p) {
        const float4 t = *reinterpret_cast<const float4*>(Fp + (4*l+u)*16 + 4*p);
        FT[4*p+0][u]=t.x; FT[4*p+1][u]=t.y; FT[4*p+2][u]=t.z; FT[4*p+3][u]=t.w;
    }

    // ---- pred_mean = F @ nm -> coalesced float4 store ----
    {
        float a0=0.f, a1=0.f, a2=0.f, a3=0.f;
        #pragma unroll
        for (int k = 0; k < 16; ++k) {
            const float m = bq(nmv[k&3], k>>2);
            a0 += FT[k][0]*m; a1 += FT[k][1]*m; a2 += FT[k][2]*m; a3 += FT[k][3]*m;
        }
        *reinterpret_cast<float4*>(g_out + (size_t)g*16 + 4*l) = make_float4(a0,a1,a2,a3);
    }

    // ---- pred_cov row-fused: for each row i,
    //      w[u] = W[i][4l+u] = sum_k F[i][k]*NC[k][4l+u]   (F[i][k] via DPP)
    //      out[i][4l+u] = Q[i][4l+u] + sum_t bq(w[t])*FT[t][u]
    //      W never materialized; 2-row Q prefetch; coalesced stores ----
    float* const out_pc = g_out + (size_t)G*16 + (size_t)g*256;
    float4 qa = *reinterpret_cast<const float4*>(Qp + 0*16 + 4*l);
    float4 qb = *reinterpret_cast<const float4*>(Qp + 1*16 + 4*l);
    #pragma unroll
    for (int i = 0; i < 16; ++i) {
        float4 qn = qb;
        if (i < 14) qn = *reinterpret_cast<const float4*>(Qp + (i+2)*16 + 4*l);
        // w = F_i @ NC (col-slab)
        float w0=0.f, w1=0.f, w2=0.f, w3=0.f;
        #pragma unroll
        for (int k = 0; k < 16; ++k) {
            const float f = bq(FT[k][i&3], i>>2);      // F[i][k]
            w0 += f*P[k][0]; w1 += f*P[k][1]; w2 += f*P[k][2]; w3 += f*P[k][3];
        }
        // out_i = w @ F^T + Q_i
        float o0=qa.x, o1=qa.y, o2=qa.z, o3=qa.w;
        #pragma unroll
        for (int t = 0; t < 16; ++t) {
            float wt;
            switch (t & 3) { case 0: wt=w0; break; case 1: wt=w1; break;
                             case 2: wt=w2; break; default: wt=w3; }
            const float wb = bq(wt, t>>2);             // W[i][t]
            o0 += wb*FT[t][0]; o1 += wb*FT[t][1]; o2 += wb*FT[t][2]; o3 += wb*FT[t][3];
        }
        *reinterpret_cast<float4*>(out_pc + i*16 + 4*l) = make_float4(o0,o1,o2,o3);
        qa = qb; qb = qn;
    }
}

extern "C" void kernel_launch(void* const* d_in, const int* in_sizes, int n_in,
                              void* d_out, int out_size, void* d_ws, size_t ws_size,
                              hipStream_t stream) {
    const float* g_in   = (const float*)d_in[0];
    const float* g_mean = (const float*)d_in[1];
    const float* g_cov  = (const float*)d_in[2];
    const float* g_H    = (const float*)d_in[3];
    const float* g_R    = (const float*)d_in[4];
    const float* g_F    = (const float*)d_in[5];
    const float* g_Q    = (const float*)d_in[6];
    float* out = (float*)d_out;
    const int G = in_sizes[2] / 256;     // cov is [G,16,16]
    kalman_kernel<<<G/64, 256, 0, stream>>>(g_in, g_mean, g_cov, g_H, g_R, g_F, g_Q, out, G);
}

// Round 11
// 155.119 us; speedup vs baseline: 4.2977x; 1.1917x over previous
//
#include <hip/hip_runtime.h>

// Batched Kalman step: G groups, S=16, M=8, fp32.
// R11 = quad-per-group all-register scheme (R8/R10) with the live-set forced
// down by CODE STRUCTURE (launch_bounds min-waves is radioactive: R4/R9):
//  - asm memory barriers between phases stop the allocator from hoisting the
//    FT/Q loads into the update phase (R10: 244 VGPR from hoisting)
//  - X never materialized: each X row streams into nm + a rank-1 NC update
//  - all GEMM math in float2 ext-vectors -> v_pk_fma_f32 (~3300 instr/lane,
//    was ~5200)
//  Target: natural VGPR <= 170 -> 3 waves/SIMD.

typedef float v2f __attribute__((ext_vector_type(2)));

#define PHASE_BARRIER() asm volatile("" ::: "memory")

__device__ __forceinline__ float bq(float x, int t) {
    // broadcast lane t of each quad (DPP quad_perm)
    switch (t & 3) {
    case 0:  return __int_as_float(__builtin_amdgcn_mov_dpp(__float_as_int(x), 0x00, 0xF, 0xF, true));
    case 1:  return __int_as_float(__builtin_amdgcn_mov_dpp(__float_as_int(x), 0x55, 0xF, 0xF, true));
    case 2:  return __int_as_float(__builtin_amdgcn_mov_dpp(__float_as_int(x), 0xAA, 0xF, 0xF, true));
    default: return __int_as_float(__builtin_amdgcn_mov_dpp(__float_as_int(x), 0xFF, 0xF, 0xF, true));
    }
}
__device__ __forceinline__ v2f splat(float c) { v2f r; r.x = c; r.y = c; return r; }

__global__ __launch_bounds__(256) void kalman_kernel(
    const float* __restrict__ g_in,
    const float* __restrict__ g_mean,
    const float* __restrict__ g_cov,
    const float* __restrict__ g_H,
    const float* __restrict__ g_R,
    const float* __restrict__ g_F,
    const float* __restrict__ g_Q,
    float* __restrict__ g_out,
    int G)
{
    const int l = threadIdx.x & 3;                         // lane in quad
    const int g = (blockIdx.x << 6) | (threadIdx.x >> 2);  // group id

    const float* const Pp = g_cov + (size_t)g * 256;
    const float* const Hp = g_H   + (size_t)g * 128;
    const float* const Rp = g_R   + (size_t)g * 64;
    const float* const Fp = g_F   + (size_t)g * 256;
    const float* const Qp = g_Q   + (size_t)g * 256;

    // ---- loads: P col-slab (cols 4l..4l+3 as 2 v2f per row) ----
    v2f Plo[16], Phi[16];
    #pragma unroll
    for (int k = 0; k < 16; ++k) {
        const float4 t = *reinterpret_cast<const float4*>(Pp + k*16 + 4*l);
        Plo[k].x=t.x; Plo[k].y=t.y; Phi[k].x=t.z; Phi[k].y=t.w;
    }
    // HT[k] = {H[2l][k], H[2l+1][k]}
    v2f HT[16];
    {
        float4 ra[4], rb[4];
        #pragma unroll
        for (int p = 0; p < 4; ++p) {
            ra[p] = *reinterpret_cast<const float4*>(Hp + (2*l  )*16 + 4*p);
            rb[p] = *reinterpret_cast<const float4*>(Hp + (2*l+1)*16 + 4*p);
        }
        #pragma unroll
        for (int p = 0; p < 4; ++p) {
            HT[4*p+0].x=ra[p].x; HT[4*p+0].y=rb[p].x;
            HT[4*p+1].x=ra[p].y; HT[4*p+1].y=rb[p].y;
            HT[4*p+2].x=ra[p].z; HT[4*p+2].y=rb[p].z;
            HT[4*p+3].x=ra[p].w; HT[4*p+3].y=rb[p].w;
        }
    }
    // S rows init R (cols 2l, 2l+1)
    v2f S[8];
    #pragma unroll
    for (int i = 0; i < 8; ++i) {
        const float2 t = *reinterpret_cast<const float2*>(Rp + i*8 + 2*l);
        S[i].x=t.x; S[i].y=t.y;
    }
    v2f mnlo, mnhi;
    { const float4 t = *reinterpret_cast<const float4*>(g_mean + (size_t)g*16 + 4*l);
      mnlo.x=t.x; mnlo.y=t.y; mnhi.x=t.z; mnhi.y=t.w; }
    v2f ipv;
    { const float2 t = *reinterpret_cast<const float2*>(g_in + (size_t)g*8 + 2*l);
      ipv.x=t.x; ipv.y=t.y; }

    // ---- CT = H@P (col-slab; H[i][k] = bq(HT[k] comp i&1, i>>1)) ----
    v2f CTlo[8], CThi[8];
    #pragma unroll
    for (int i = 0; i < 8; ++i) {
        v2f alo = {0.f, 0.f}, ahi = {0.f, 0.f};
        #pragma unroll
        for (int k = 0; k < 16; ++k) {
            const float h = bq((i&1) ? HT[k].y : HT[k].x, i>>1);
            alo += splat(h) * Plo[k];
            ahi += splat(h) * Phi[k];
        }
        CTlo[i]=alo; CThi[i]=ahi;
    }

    // ---- S = CT@H^T + R  (CT[i][k] = bq(CT{lo,hi}[i] comp, k>>2)) ----
    #pragma unroll
    for (int i = 0; i < 8; ++i) {
        v2f acc = S[i];
        #pragma unroll
        for (int k = 0; k < 16; ++k) {
            const float c = bq((k&2) ? ((k&1)?CThi[i].y:CThi[i].x)
                                     : ((k&1)?CTlo[i].y:CTlo[i].x), k>>2);
            acc += splat(c) * HT[k];
        }
        S[i] = acc;
    }

    // ---- res = inp - H@mean ----
    v2f resd = ipv;
    #pragma unroll
    for (int k = 0; k < 16; ++k) {
        const float m = bq((k&2) ? ((k&1)?mnhi.y:mnhi.x)
                                 : ((k&1)?mnlo.y:mnlo.x), k>>2);
        resd -= splat(m) * HT[k];
    }

    // ---- Gauss-Jordan [S | I] -> Sinv (cols 2l,2l+1; divergence-free) ----
    v2f Ii[8];
    #pragma unroll
    for (int i = 0; i < 8; ++i) {
        Ii[i].x = (2*l   == i) ? 1.f : 0.f;
        Ii[i].y = (2*l+1 == i) ? 1.f : 0.f;
    }
    float pinvD[8];
    #pragma unroll
    for (int k = 0; k < 8; ++k) {
        const float pv   = bq((k&1) ? S[k].y : S[k].x, k>>1);
        const float pinv = __builtin_amdgcn_rcpf(pv);
        pinvD[k] = pinv;
        #pragma unroll
        for (int i = 0; i < 8; ++i) {
            if (i == k) continue;
            const float fi = bq((k&1) ? S[i].y : S[i].x, k>>1) * pinv;
            S[i]  -= splat(fi) * S[k];
            Ii[i] -= splat(fi) * Ii[k];
        }
    }
    #pragma unroll
    for (int i = 0; i < 8; ++i) Ii[i] *= splat(pinvD[i]);

    // ---- stream X rows: nm += X[m]*res ; NC(P) -= CT^T[.,m] (x) X[m] ----
    v2f nmL = mnlo, nmH = mnhi;
    #pragma unroll
    for (int m = 0; m < 8; ++m) {
        v2f xlo = {0.f,0.f}, xhi = {0.f,0.f};
        #pragma unroll
        for (int j = 0; j < 8; ++j) {
            const float s = bq((j&1) ? Ii[m].y : Ii[m].x, j>>1);
            xlo += splat(s) * CTlo[j];
            xhi += splat(s) * CThi[j];
        }
        const float r = bq((m&1) ? resd.y : resd.x, m>>1);
        nmL += splat(r) * xlo;
        nmH += splat(r) * xhi;
        #pragma unroll
        for (int s2 = 0; s2 < 16; ++s2) {
            const float c = bq((s2&2) ? ((s2&1)?CThi[m].y:CThi[m].x)
                                      : ((s2&1)?CTlo[m].y:CTlo[m].x), s2>>2);
            Plo[s2] -= splat(c) * xlo;
            Phi[s2] -= splat(c) * xhi;
        }
    }
    // P now holds NC. CT/S/Ii/HT/resd dead.
    PHASE_BARRIER();

    // ---- FT loads: FT[t] cols {0,1}=lo {2,3}=hi, FT[t][u] = F[4l+u][t] ----
    v2f FTlo[16], FThi[16];
    {
        #pragma unroll
        for (int p = 0; p < 4; ++p) {
            const float4 r0 = *reinterpret_cast<const float4*>(Fp + (4*l+0)*16 + 4*p);
            const float4 r1 = *reinterpret_cast<const float4*>(Fp + (4*l+1)*16 + 4*p);
            const float4 r2 = *reinterpret_cast<const float4*>(Fp + (4*l+2)*16 + 4*p);
            const float4 r3 = *reinterpret_cast<const float4*>(Fp + (4*l+3)*16 + 4*p);
            FTlo[4*p+0].x=r0.x; FTlo[4*p+0].y=r1.x; FThi[4*p+0].x=r2.x; FThi[4*p+0].y=r3.x;
            FTlo[4*p+1].x=r0.y; FTlo[4*p+1].y=r1.y; FThi[4*p+1].x=r2.y; FThi[4*p+1].y=r3.y;
            FTlo[4*p+2].x=r0.z; FTlo[4*p+2].y=r1.z; FThi[4*p+2].x=r2.z; FThi[4*p+2].y=r3.z;
            FTlo[4*p+3].x=r0.w; FTlo[4*p+3].y=r1.w; FThi[4*p+3].x=r2.w; FThi[4*p+3].y=r3.w;
        }
    }

    // ---- pred_mean = F @ nm -> coalesced float4 ----
    {
        v2f plo = {0.f,0.f}, phi = {0.f,0.f};
        #pragma unroll
        for (int k = 0; k < 16; ++k) {
            const float m = bq((k&2) ? ((k&1)?nmH.y:nmH.x)
                                     : ((k&1)?nmL.y:nmL.x), k>>2);
            plo += splat(m) * FTlo[k];
            phi += splat(m) * FThi[k];
        }
        *reinterpret_cast<float4*>(g_out + (size_t)g*16 + 4*l) =
            make_float4(plo.x, plo.y, phi.x, phi.y);
    }

    // ---- pred_cov rows, fused W=F@NC then out=W@F^T+Q (2-row Q prefetch) ----
    float* const out_pc = g_out + (size_t)G*16 + (size_t)g*256;
    float4 qa = *reinterpret_cast<const float4*>(Qp + 0*16 + 4*l);
    float4 qb = *reinterpret_cast<const float4*>(Qp + 1*16 + 4*l);
    #pragma unroll
    for (int i = 0; i < 16; ++i) {
        float4 qn = qb;
        if (i < 14) qn = *reinterpret_cast<const float4*>(Qp + (i+2)*16 + 4*l);
        // w = F_i @ NC  (F[i][k] = bq(FT[k] comp i&3, i>>2))
        v2f wlo = {0.f,0.f}, whi = {0.f,0.f};
        #pragma unroll
        for (int k = 0; k < 16; ++k) {
            const float f = bq((i&2) ? ((i&1)?FThi[k].y:FThi[k].x)
                                     : ((i&1)?FTlo[k].y:FTlo[k].x), i>>2);
            wlo += splat(f) * Plo[k];
            whi += splat(f) * Phi[k];
        }
        // out_i = w @ F^T + Q_i  (W[i][t] = bq(w comp t&3, t>>2))
        v2f olo; olo.x=qa.x; olo.y=qa.y;
        v2f ohi; ohi.x=qa.z; ohi.y=qa.w;
        #pragma unroll
        for (int t = 0; t < 16; ++t) {
            const float wb = bq((t&2) ? ((t&1)?whi.y:whi.x)
                                      : ((t&1)?wlo.y:wlo.x), t>>2);
            olo += splat(wb) * FTlo[t];
            ohi += splat(wb) * FThi[t];
        }
        *reinterpret_cast<float4*>(out_pc + i*16 + 4*l) =
            make_float4(olo.x, olo.y, ohi.x, ohi.y);
        qa = qb; qb = qn;
    }
}

extern "C" void kernel_launch(void* const* d_in, const int* in_sizes, int n_in,
                              void* d_out, int out_size, void* d_ws, size_t ws_size,
                              hipStream_t stream) {
    const float* g_in   = (const float*)d_in[0];
    const float* g_mean = (const float*)d_in[1];
    const float* g_cov  = (const float*)d_in[2];
    const float* g_H    = (const float*)d_in[3];
    const float* g_R    = (const float*)d_in[4];
    const float* g_F    = (const float*)d_in[5];
    const float* g_Q    = (const float*)d_in[6];
    float* out = (float*)d_out;
    const int G = in_sizes[2] / 256;     // cov is [G,16,16]
    kalman_kernel<<<G/64, 256, 0, stream>>>(g_in, g_mean, g_cov, g_H, g_R, g_F, g_Q, out, G);
}

// Round 12
// 135.749 us; speedup vs baseline: 4.9110x; 1.1427x over previous
//
#include <hip/hip_runtime.h>

// Batched Kalman step: G groups, S=16, M=8, fp32.
// R12 = R11 (quad-per-group, all-register, DPP broadcasts, packed v2f math)
// + deep prefetch. Occupancy is pinned at 2 waves/SIMD for any VGPR in
// (128,256] (m68/m69 granularity; R8=192, R10=244, R11=132 all showed 10.6%),
// and the fused epilogue needs ~138 live regs, so <=128 is structurally out.
// => spend the FREE headroom up to ~250 VGPR on latency:
//  - FT (8x dwordx4) and a 6-deep rolling Q prefetch are issued right after
//    the GJ solve, so the ~1200cy stream-X phase hides their HBM latency
//    (Q is 134 MB -> never L2-resident -> ~900cy; old 2-deep lookahead
//    exposed ~500cy x 16 rows per wave)
//  - epilogue Q lookahead = 6 rows (~1200cy of compute)
// All prefetch-buffer indices are compile-time (full unroll; rule #20).

typedef float v2f __attribute__((ext_vector_type(2)));

__device__ __forceinline__ float bq(float x, int t) {
    // broadcast lane t of each quad (DPP quad_perm)
    switch (t & 3) {
    case 0:  return __int_as_float(__builtin_amdgcn_mov_dpp(__float_as_int(x), 0x00, 0xF, 0xF, true));
    case 1:  return __int_as_float(__builtin_amdgcn_mov_dpp(__float_as_int(x), 0x55, 0xF, 0xF, true));
    case 2:  return __int_as_float(__builtin_amdgcn_mov_dpp(__float_as_int(x), 0xAA, 0xF, 0xF, true));
    default: return __int_as_float(__builtin_amdgcn_mov_dpp(__float_as_int(x), 0xFF, 0xF, 0xF, true));
    }
}
__device__ __forceinline__ v2f splat(float c) { v2f r; r.x = c; r.y = c; return r; }

__global__ __launch_bounds__(256) void kalman_kernel(
    const float* __restrict__ g_in,
    const float* __restrict__ g_mean,
    const float* __restrict__ g_cov,
    const float* __restrict__ g_H,
    const float* __restrict__ g_R,
    const float* __restrict__ g_F,
    const float* __restrict__ g_Q,
    float* __restrict__ g_out,
    int G)
{
    const int l = threadIdx.x & 3;                         // lane in quad
    const int g = (blockIdx.x << 6) | (threadIdx.x >> 2);  // group id

    const float* const Pp = g_cov + (size_t)g * 256;
    const float* const Hp = g_H   + (size_t)g * 128;
    const float* const Rp = g_R   + (size_t)g * 64;
    const float* const Fp = g_F   + (size_t)g * 256;
    const float* const Qp = g_Q   + (size_t)g * 256;

    // ---- loads: P col-slab (cols 4l..4l+3 as 2 v2f per row) ----
    v2f Plo[16], Phi[16];
    #pragma unroll
    for (int k = 0; k < 16; ++k) {
        const float4 t = *reinterpret_cast<const float4*>(Pp + k*16 + 4*l);
        Plo[k].x=t.x; Plo[k].y=t.y; Phi[k].x=t.z; Phi[k].y=t.w;
    }
    // HT[k] = {H[2l][k], H[2l+1][k]}
    v2f HT[16];
    {
        float4 ra[4], rb[4];
        #pragma unroll
        for (int p = 0; p < 4; ++p) {
            ra[p] = *reinterpret_cast<const float4*>(Hp + (2*l  )*16 + 4*p);
            rb[p] = *reinterpret_cast<const float4*>(Hp + (2*l+1)*16 + 4*p);
        }
        #pragma unroll
        for (int p = 0; p < 4; ++p) {
            HT[4*p+0].x=ra[p].x; HT[4*p+0].y=rb[p].x;
            HT[4*p+1].x=ra[p].y; HT[4*p+1].y=rb[p].y;
            HT[4*p+2].x=ra[p].z; HT[4*p+2].y=rb[p].z;
            HT[4*p+3].x=ra[p].w; HT[4*p+3].y=rb[p].w;
        }
    }
    // S rows init R (cols 2l, 2l+1)
    v2f S[8];
    #pragma unroll
    for (int i = 0; i < 8; ++i) {
        const float2 t = *reinterpret_cast<const float2*>(Rp + i*8 + 2*l);
        S[i].x=t.x; S[i].y=t.y;
    }
    v2f mnlo, mnhi;
    { const float4 t = *reinterpret_cast<const float4*>(g_mean + (size_t)g*16 + 4*l);
      mnlo.x=t.x; mnlo.y=t.y; mnhi.x=t.z; mnhi.y=t.w; }
    v2f ipv;
    { const float2 t = *reinterpret_cast<const float2*>(g_in + (size_t)g*8 + 2*l);
      ipv.x=t.x; ipv.y=t.y; }

    // ---- CT = H@P (col-slab; H[i][k] = bq(HT[k] comp i&1, i>>1)) ----
    v2f CTlo[8], CThi[8];
    #pragma unroll
    for (int i = 0; i < 8; ++i) {
        v2f alo = {0.f, 0.f}, ahi = {0.f, 0.f};
        #pragma unroll
        for (int k = 0; k < 16; ++k) {
            const float h = bq((i&1) ? HT[k].y : HT[k].x, i>>1);
            alo += splat(h) * Plo[k];
            ahi += splat(h) * Phi[k];
        }
        CTlo[i]=alo; CThi[i]=ahi;
    }

    // ---- S = CT@H^T + R ----
    #pragma unroll
    for (int i = 0; i < 8; ++i) {
        v2f acc = S[i];
        #pragma unroll
        for (int k = 0; k < 16; ++k) {
            const float c = bq((k&2) ? ((k&1)?CThi[i].y:CThi[i].x)
                                     : ((k&1)?CTlo[i].y:CTlo[i].x), k>>2);
            acc += splat(c) * HT[k];
        }
        S[i] = acc;
    }

    // ---- res = inp - H@mean ----
    v2f resd = ipv;
    #pragma unroll
    for (int k = 0; k < 16; ++k) {
        const float m = bq((k&2) ? ((k&1)?mnhi.y:mnhi.x)
                                 : ((k&1)?mnlo.y:mnlo.x), k>>2);
        resd -= splat(m) * HT[k];
    }

    // ---- Gauss-Jordan [S | I] -> Sinv (divergence-free) ----
    v2f Ii[8];
    #pragma unroll
    for (int i = 0; i < 8; ++i) {
        Ii[i].x = (2*l   == i) ? 1.f : 0.f;
        Ii[i].y = (2*l+1 == i) ? 1.f : 0.f;
    }
    float pinvD[8];
    #pragma unroll
    for (int k = 0; k < 8; ++k) {
        const float pv   = bq((k&1) ? S[k].y : S[k].x, k>>1);
        const float pinv = __builtin_amdgcn_rcpf(pv);
        pinvD[k] = pinv;
        #pragma unroll
        for (int i = 0; i < 8; ++i) {
            if (i == k) continue;
            const float fi = bq((k&1) ? S[i].y : S[i].x, k>>1) * pinv;
            S[i]  -= splat(fi) * S[k];
            Ii[i] -= splat(fi) * Ii[k];
        }
    }
    #pragma unroll
    for (int i = 0; i < 8; ++i) Ii[i] *= splat(pinvD[i]);

    // ==== PREFETCH: issue FT + first 6 Q rows NOW; the ~1200cy stream-X
    //      phase below hides their HBM latency (free VGPR headroom) ====
    v2f FTlo[16], FThi[16];
    {
        #pragma unroll
        for (int p = 0; p < 4; ++p) {
            const float4 r0 = *reinterpret_cast<const float4*>(Fp + (4*l+0)*16 + 4*p);
            const float4 r1 = *reinterpret_cast<const float4*>(Fp + (4*l+1)*16 + 4*p);
            const float4 r2 = *reinterpret_cast<const float4*>(Fp + (4*l+2)*16 + 4*p);
            const float4 r3 = *reinterpret_cast<const float4*>(Fp + (4*l+3)*16 + 4*p);
            FTlo[4*p+0].x=r0.x; FTlo[4*p+0].y=r1.x; FThi[4*p+0].x=r2.x; FThi[4*p+0].y=r3.x;
            FTlo[4*p+1].x=r0.y; FTlo[4*p+1].y=r1.y; FThi[4*p+1].x=r2.y; FThi[4*p+1].y=r3.y;
            FTlo[4*p+2].x=r0.z; FTlo[4*p+2].y=r1.z; FThi[4*p+2].x=r2.z; FThi[4*p+2].y=r3.z;
            FTlo[4*p+3].x=r0.w; FTlo[4*p+3].y=r1.w; FThi[4*p+3].x=r2.w; FThi[4*p+3].y=r3.w;
        }
    }
    float4 qbuf[6];
    #pragma unroll
    for (int i = 0; i < 6; ++i)
        qbuf[i] = *reinterpret_cast<const float4*>(Qp + i*16 + 4*l);

    // ---- stream X rows: nm += X[m]*res ; NC(P) -= CT^T[.,m] (x) X[m] ----
    v2f nmL = mnlo, nmH = mnhi;
    #pragma unroll
    for (int m = 0; m < 8; ++m) {
        v2f xlo = {0.f,0.f}, xhi = {0.f,0.f};
        #pragma unroll
        for (int j = 0; j < 8; ++j) {
            const float s = bq((j&1) ? Ii[m].y : Ii[m].x, j>>1);
            xlo += splat(s) * CTlo[j];
            xhi += splat(s) * CThi[j];
        }
        const float r = bq((m&1) ? resd.y : resd.x, m>>1);
        nmL += splat(r) * xlo;
        nmH += splat(r) * xhi;
        #pragma unroll
        for (int s2 = 0; s2 < 16; ++s2) {
            const float c = bq((s2&2) ? ((s2&1)?CThi[m].y:CThi[m].x)
                                      : ((s2&1)?CTlo[m].y:CTlo[m].x), s2>>2);
            Plo[s2] -= splat(c) * xlo;
            Phi[s2] -= splat(c) * xhi;
        }
    }
    // P now holds NC. CT/S/Ii/HT/resd dead.

    // ---- pred_mean = F @ nm -> coalesced float4 ----
    {
        v2f plo = {0.f,0.f}, phi = {0.f,0.f};
        #pragma unroll
        for (int k = 0; k < 16; ++k) {
            const float m = bq((k&2) ? ((k&1)?nmH.y:nmH.x)
                                     : ((k&1)?nmL.y:nmL.x), k>>2);
            plo += splat(m) * FTlo[k];
            phi += splat(m) * FThi[k];
        }
        *reinterpret_cast<float4*>(g_out + (size_t)g*16 + 4*l) =
            make_float4(plo.x, plo.y, phi.x, phi.y);
    }

    // ---- pred_cov rows, fused W=F@NC then out=W@F^T+Q
    //      (6-deep rolling Q prefetch; all indices compile-time) ----
    float* const out_pc = g_out + (size_t)G*16 + (size_t)g*256;
    #pragma unroll
    for (int i = 0; i < 16; ++i) {
        // w = F_i @ NC  (F[i][k] = bq(FT[k] comp i&3, i>>2))
        v2f wlo = {0.f,0.f}, whi = {0.f,0.f};
        #pragma unroll
        for (int k = 0; k < 16; ++k) {
            const float f = bq((i&2) ? ((i&1)?FThi[k].y:FThi[k].x)
                                     : ((i&1)?FTlo[k].y:FTlo[k].x), i>>2);
            wlo += splat(f) * Plo[k];
            whi += splat(f) * Phi[k];
        }
        // out_i = w @ F^T + Q_i
        const float4 qv = qbuf[i % 6];
        if (i + 6 < 16)
            qbuf[i % 6] = *reinterpret_cast<const float4*>(Qp + (i+6)*16 + 4*l);
        v2f olo; olo.x=qv.x; olo.y=qv.y;
        v2f ohi; ohi.x=qv.z; ohi.y=qv.w;
        #pragma unroll
        for (int t = 0; t < 16; ++t) {
            const float wb = bq((t&2) ? ((t&1)?whi.y:whi.x)
                                      : ((t&1)?wlo.y:wlo.x), t>>2);
            olo += splat(wb) * FTlo[t];
            ohi += splat(wb) * FThi[t];
        }
        *reinterpret_cast<float4*>(out_pc + i*16 + 4*l) =
            make_float4(olo.x, olo.y, ohi.x, ohi.y);
    }
}

extern "C" void kernel_launch(void* const* d_in, const int* in_sizes, int n_in,
                              void* d_out, int out_size, void* d_ws, size_t ws_size,
                              hipStream_t stream) {
    const float* g_in   = (const float*)d_in[0];
    const float* g_mean = (const float*)d_in[1];
    const float* g_cov  = (const float*)d_in[2];
    const float* g_H    = (const float*)d_in[3];
    const float* g_R    = (const float*)d_in[4];
    const float* g_F    = (const float*)d_in[5];
    const float* g_Q    = (const float*)d_in[6];
    float* out = (float*)d_out;
    const int G = in_sizes[2] / 256;     // cov is [G,16,16]
    kalman_kernel<<<G/64, 256, 0, stream>>>(g_in, g_mean, g_cov, g_H, g_R, g_F, g_Q, out, G);
}